// Round 1
// baseline (15029.012 us; speedup 1.0000x reference)
//
#include <hip/hip_runtime.h>
#include <hip/hip_fp16.h>

#define T_DIM 1024
#define B_DIM 64
#define F_DIM 512
#define H_DIM 512
#define G4    2048
#define HSZ   (B_DIM*H_DIM)   // 32768

typedef _Float16 h16;
typedef _Float16 v8h __attribute__((ext_vector_type(8)));
typedef _Float16 v4h __attribute__((ext_vector_type(4)));
typedef _Float16 v2h __attribute__((ext_vector_type(2)));
typedef float    v4f __attribute__((ext_vector_type(4)));

// workspace layout (bytes):
//   [0, 256MB)            xp arranged: h16 [T][256 wg][2 tile][64 lane][4 reg]
//   [+0, +128KB)          hbuf: h16 [2][64][512] double-buffered h
//   [+128KB, +128KB+1KB)  16 barrier counters, 64B apart
#define XP_HALVES ((size_t)T_DIM * 256 * 2 * 64 * 4)
#define XP_BYTES  (XP_HALVES * 2)
#define HB_BYTES  ((size_t)2 * HSZ * 2)
#define CTR_BYTES ((size_t)256 * 4)

// ---------------------------------------------------------------------------
// Phase 1: x_proj = X @ Wx + b, stored as fp16 in MFMA C/D fragment layout.
// Permuted column index pc = ub*32 + T*16 + n ; gate = T*2 + (n>>3);
// gcol = gate*512 + ub*8 + (n&7).  One 16x16 tile == one (t, wg2, T) fragment.
// ---------------------------------------------------------------------------
__global__ __launch_bounds__(256) void xproj_kernel(
    const float* __restrict__ X, const float* __restrict__ Wx,
    const float* __restrict__ bias, h16* __restrict__ xp)
{
  __shared__ __align__(16) h16 As[128*72];   // [m 0..127][k 0..63], pad 72
  __shared__ __align__(16) h16 Bs[128*72];   // [pc 0..127][k 0..63], pad 72
  const int wgid = blockIdx.x;               // 8192 blocks
  const int wgn  = wgid & 15;                // Wx-column block (128 pc)
  const int bg   = (wgid >> 4) & 3;          // batch group (16 rows)
  const int t0   = (wgid >> 6) * 8;          // 8 consecutive t per WG
  const int tid  = threadIdx.x;
  const int lane = tid & 63;
  const int wv   = tid >> 6;
  const int mh   = wv & 1, nh = wv >> 1;
  const int n    = lane & 15, quad = lane >> 4;

  v4f acc[4][4];
  #pragma unroll
  for (int mi = 0; mi < 4; ++mi)
    #pragma unroll
    for (int ni = 0; ni < 4; ++ni) acc[mi][ni] = {0.f, 0.f, 0.f, 0.f};

  for (int kc = 0; kc < 8; ++kc) {
    __syncthreads();
    // stage A: rows m=(tl*16+bl) -> X[bg*16+bl][t0+tl][kc*64 + k]
    {
      const int am  = tid >> 1;
      const int ak0 = (tid & 1) * 32;
      const int abl = am & 15, atl = am >> 4;
      const float* asrc = X + (((size_t)(bg*16 + abl))*T_DIM + (t0 + atl))*F_DIM
                            + kc*64 + ak0;
      h16* adst = As + am*72 + ak0;
      #pragma unroll
      for (int j = 0; j < 32; j += 4) {
        float4 v = *(const float4*)(asrc + j);
        v4h w = { (h16)v.x, (h16)v.y, (h16)v.z, (h16)v.w };
        *(v4h*)(adst + j) = w;
      }
    }
    // stage B: Bs[pc][k] = Wx[kc*64+k][gcol(pc)]
    #pragma unroll
    for (int it = 0; it < 16; ++it) {
      int idx = it*256 + tid;
      int pc  = idx & 127;
      int kp  = idx >> 7;                  // 0..31 (2 k's per thread)
      int pcg = wgn*128 + pc;
      int ub  = pcg >> 5, Tt = (pcg >> 4) & 1, nn = pcg & 15;
      int gcol = (Tt*2 + (nn >> 3))*512 + ub*8 + (nn & 7);
      const float* wsrc = Wx + (size_t)(kc*64 + kp*2)*G4 + gcol;
      v2h w = { (h16)wsrc[0], (h16)wsrc[G4] };
      *(v2h*)(Bs + pc*72 + kp*2) = w;
    }
    __syncthreads();
    #pragma unroll
    for (int kk = 0; kk < 2; ++kk) {
      v8h aF[4], bF[4];
      #pragma unroll
      for (int mi = 0; mi < 4; ++mi)
        aF[mi] = *(const v8h*)(As + ((mh*4 + mi)*16 + n)*72 + kk*32 + quad*8);
      #pragma unroll
      for (int ni = 0; ni < 4; ++ni)
        bF[ni] = *(const v8h*)(Bs + ((nh*4 + ni)*16 + n)*72 + kk*32 + quad*8);
      #pragma unroll
      for (int mi = 0; mi < 4; ++mi)
        #pragma unroll
        for (int ni = 0; ni < 4; ++ni)
          acc[mi][ni] = __builtin_amdgcn_mfma_f32_16x16x32_f16(
              aF[mi], bF[ni], acc[mi][ni], 0, 0, 0);
    }
  }
  // epilogue: + bias, fp32->fp16, store arranged fragments
  #pragma unroll
  for (int ni = 0; ni < 4; ++ni) {
    int pc0  = wgn*128 + (nh*4 + ni)*16;
    int ub   = pc0 >> 5, Tt = (pc0 >> 4) & 1;
    int gcol = (Tt*2 + (n >> 3))*512 + ub*8 + (n & 7);
    float bv = bias[gcol];
    int wg2  = bg*64 + ub;
    #pragma unroll
    for (int mi = 0; mi < 4; ++mi) {
      int t = t0 + mh*4 + mi;
      size_t off = ((((size_t)t*256 + wg2)*2 + Tt)*256) + lane*4;
      v4h o = { (h16)(acc[mi][ni][0] + bv), (h16)(acc[mi][ni][1] + bv),
                (h16)(acc[mi][ni][2] + bv), (h16)(acc[mi][ni][3] + bv) };
      *(v4h*)(xp + off) = o;
    }
  }
}

// ---------------------------------------------------------------------------
// Phase 2: persistent scan. 256 single-wave WGs; wg = bg*64 + ub.
// Each WG: 16 batch rows (bg) x 8 hidden units (ub), all 4 gates.
// Wh slice lives in 128 VGPRs as B-fragments. c-state in VGPRs.
// h exchanged via double-buffered global fp16 + device-scope barrier.
// ---------------------------------------------------------------------------
__device__ __forceinline__ float fsig(float x) {
  return __builtin_amdgcn_rcpf(1.f + __expf(-x));
}
__device__ __forceinline__ float ftanh(float x) {
  return 1.f - 2.f * __builtin_amdgcn_rcpf(__expf(2.f*x) + 1.f);
}

__global__ __launch_bounds__(64, 1) void scan_kernel(
    const float* __restrict__ Wh, const h16* __restrict__ xp,
    h16* __restrict__ hbuf, unsigned* __restrict__ ctr,
    float* __restrict__ out)
{
  const int wg   = blockIdx.x;          // 0..255
  const int lane = threadIdx.x;         // 0..63
  const int bg   = wg >> 6, ub = wg & 63;
  const int r0   = bg*16,  u0 = ub*8;
  const int n    = lane & 15, quad = lane >> 4;

  __shared__ float gbuf[16*33];         // [row r][32 gate-cols], pad 33

  // persistent B fragments: tile0 = gates {i,f}, tile1 = {g,o}
  v8h bF0[16], bF1[16];
  {
    const int g01 = n >> 3;
    const int uc  = u0 + (n & 7);
    #pragma unroll
    for (int kk = 0; kk < 16; ++kk) {
      const int kb = kk*32 + quad*8;
      v8h f0, f1;
      #pragma unroll
      for (int j = 0; j < 8; ++j) {
        f0[j] = (h16)Wh[(size_t)(kb + j)*G4 + (g01*512 + uc)];
        f1[j] = (h16)Wh[(size_t)(kb + j)*G4 + ((2 + g01)*512 + uc)];
      }
      bF0[kk] = f0; bF1[kk] = f1;
    }
  }

  float c0 = 0.f, c1 = 0.f, hf0 = 0.f, hf1 = 0.f;
  unsigned* myc = ctr + (wg & 15)*16;   // 16 WGs per counter line

  for (int t = 0; t < T_DIM; ++t) {
    const int p = t & 1;
    // xp fragment loads (independent of h -> issue before the wait)
    const size_t xoff = (((size_t)t*256 + wg)*2)*256 + lane*4;
    v4h x0 = *(const v4h*)(xp + xoff);
    v4h x1 = *(const v4h*)(xp + xoff + 256);

    if (t) {
      const unsigned target = (unsigned)t * 16u;
      for (;;) {
        unsigned v = target;
        if (lane < 16)
          v = __hip_atomic_load(ctr + lane*16, __ATOMIC_RELAXED,
                                __HIP_MEMORY_SCOPE_AGENT);
        if (__all((int)(v >= target))) break;
        __builtin_amdgcn_s_sleep(1);
      }
      __builtin_amdgcn_fence(__ATOMIC_ACQUIRE, "agent");
    }

    v4f acc0 = { (float)x0[0], (float)x0[1], (float)x0[2], (float)x0[3] };
    v4f acc1 = { (float)x1[0], (float)x1[1], (float)x1[2], (float)x1[3] };
    const h16* hb = hbuf + (size_t)p*HSZ + (size_t)(r0 + n)*H_DIM + quad*8;
    #pragma unroll
    for (int kk = 0; kk < 16; ++kk) {
      v8h a = *(const v8h*)(hb + kk*32);
      acc0 = __builtin_amdgcn_mfma_f32_16x16x32_f16(a, bF0[kk], acc0, 0, 0, 0);
      acc1 = __builtin_amdgcn_mfma_f32_16x16x32_f16(a, bF1[kk], acc1, 0, 0, 0);
    }
    // gate exchange: C/D layout col=lane&15, row=quad*4+reg
    #pragma unroll
    for (int r = 0; r < 4; ++r) {
      const int row = quad*4 + r;
      gbuf[row*33 + n]      = acc0[r];   // gates 0,1 (cols 0..15)
      gbuf[row*33 + 16 + n] = acc1[r];   // gates 2,3 (cols 16..31)
    }
    __syncthreads();
    const float* gr = gbuf + n*33;       // this lane's row r = n
    const int ua = quad*2;               // local units ua, ua+1
    float gi0 = gr[ua],     gf0 = gr[8+ua],   gg0 = gr[16+ua], go0 = gr[24+ua];
    float gi1 = gr[ua+1],   gf1 = gr[9+ua],   gg1 = gr[17+ua], go1 = gr[25+ua];
    __syncthreads();                     // reads done before next-iter writes

    gi0 = fsig(gi0); gf0 = fsig(gf0); gg0 = ftanh(gg0); go0 = fsig(go0);
    gi1 = fsig(gi1); gf1 = fsig(gf1); gg1 = ftanh(gg1); go1 = fsig(go1);
    c0 = gf0*c0 + gi0*gg0;  hf0 = go0*ftanh(c0);
    c1 = gf1*c1 + gi1*gg1;  hf1 = go1*ftanh(c1);

    h16* hw = hbuf + (size_t)(p^1)*HSZ + (size_t)(r0 + n)*H_DIM + u0 + quad*2;
    v2h w = { (h16)hf0, (h16)hf1 };
    *(v2h*)hw = w;

    if (t < T_DIM - 1) {
      if (lane == 0)
        __hip_atomic_fetch_add(myc, 1u, __ATOMIC_RELEASE,
                               __HIP_MEMORY_SCOPE_AGENT);
    }
  }
  // final carry: out[0:32768] = c, out[32768:65536] = h  (fp32)
  float* oc = out + (size_t)(r0 + n)*H_DIM + u0 + quad*2;
  oc[0] = c0; oc[1] = c1;
  oc[HSZ + 0] = hf0; oc[HSZ + 1] = hf1;
}

extern "C" void kernel_launch(void* const* d_in, const int* in_sizes, int n_in,
                              void* d_out, int out_size, void* d_ws, size_t ws_size,
                              hipStream_t stream) {
  const float* X    = (const float*)d_in[0];
  const float* Wx   = (const float*)d_in[1];
  const float* Wh   = (const float*)d_in[2];
  const float* bias = (const float*)d_in[3];
  float* out = (float*)d_out;

  char* ws = (char*)d_ws;
  h16*      xp   = (h16*)ws;
  h16*      hbuf = (h16*)(ws + XP_BYTES);
  unsigned* ctr  = (unsigned*)(ws + XP_BYTES + HB_BYTES);

  // zero h double-buffer + barrier counters (ws is poisoned 0xAA each call)
  hipMemsetAsync(ws + XP_BYTES, 0, HB_BYTES + CTR_BYTES, stream);

  xproj_kernel<<<8192, 256, 0, stream>>>(X, Wx, bias, xp);
  scan_kernel<<<256, 64, 0, stream>>>(Wh, xp, hbuf, ctr, out);
}

// Round 2
// 5645.255 us; speedup vs baseline: 2.6622x; 2.6622x over previous
//
#include <hip/hip_runtime.h>
#include <hip/hip_fp16.h>

#define T_DIM 1024
#define B_DIM 64
#define F_DIM 512
#define H_DIM 512
#define G4    2048
#define HSZ   (B_DIM*H_DIM)   // 32768

typedef _Float16 h16;
typedef unsigned long long u64;
typedef _Float16 v8h __attribute__((ext_vector_type(8)));
typedef _Float16 v4h __attribute__((ext_vector_type(4)));
typedef _Float16 v2h __attribute__((ext_vector_type(2)));
typedef float    v4f __attribute__((ext_vector_type(4)));

// workspace layout (bytes):
//   [0, 256MB)                xp arranged: h16 [T][256 wg][2 tile][64 lane][4 reg]
//   [+0, +128KB)              hbuf: h16 [2][64][512] double-buffered h
//   [+128KB, +128KB+1KB)      flags: u32 [4 group][64 producer] epoch counters
#define XP_HALVES ((size_t)T_DIM * 256 * 2 * 64 * 4)
#define XP_BYTES  (XP_HALVES * 2)
#define HB_BYTES  ((size_t)2 * HSZ * 2)
#define FLG_BYTES ((size_t)256 * 4)

// ---------------------------------------------------------------------------
// Phase 1: x_proj = X @ Wx + b, stored as fp16 in MFMA C/D fragment layout.
// ---------------------------------------------------------------------------
__global__ __launch_bounds__(256) void xproj_kernel(
    const float* __restrict__ X, const float* __restrict__ Wx,
    const float* __restrict__ bias, h16* __restrict__ xp)
{
  __shared__ __align__(16) h16 As[128*72];   // [m 0..127][k 0..63], pad 72
  __shared__ __align__(16) h16 Bs[128*72];   // [pc 0..127][k 0..63], pad 72
  const int wgid = blockIdx.x;               // 8192 blocks
  const int wgn  = wgid & 15;                // Wx-column block (128 pc)
  const int bg   = (wgid >> 4) & 3;          // batch group (16 rows)
  const int t0   = (wgid >> 6) * 8;          // 8 consecutive t per WG
  const int tid  = threadIdx.x;
  const int lane = tid & 63;
  const int wv   = tid >> 6;
  const int mh   = wv & 1, nh = wv >> 1;
  const int n    = lane & 15, quad = lane >> 4;

  v4f acc[4][4];
  #pragma unroll
  for (int mi = 0; mi < 4; ++mi)
    #pragma unroll
    for (int ni = 0; ni < 4; ++ni) acc[mi][ni] = {0.f, 0.f, 0.f, 0.f};

  for (int kc = 0; kc < 8; ++kc) {
    __syncthreads();
    {
      const int am  = tid >> 1;
      const int ak0 = (tid & 1) * 32;
      const int abl = am & 15, atl = am >> 4;
      const float* asrc = X + (((size_t)(bg*16 + abl))*T_DIM + (t0 + atl))*F_DIM
                            + kc*64 + ak0;
      h16* adst = As + am*72 + ak0;
      #pragma unroll
      for (int j = 0; j < 32; j += 4) {
        float4 v = *(const float4*)(asrc + j);
        v4h w = { (h16)v.x, (h16)v.y, (h16)v.z, (h16)v.w };
        *(v4h*)(adst + j) = w;
      }
    }
    #pragma unroll
    for (int it = 0; it < 16; ++it) {
      int idx = it*256 + tid;
      int pc  = idx & 127;
      int kp  = idx >> 7;
      int pcg = wgn*128 + pc;
      int ub  = pcg >> 5, Tt = (pcg >> 4) & 1, nn = pcg & 15;
      int gcol = (Tt*2 + (nn >> 3))*512 + ub*8 + (nn & 7);
      const float* wsrc = Wx + (size_t)(kc*64 + kp*2)*G4 + gcol;
      v2h w = { (h16)wsrc[0], (h16)wsrc[G4] };
      *(v2h*)(Bs + pc*72 + kp*2) = w;
    }
    __syncthreads();
    #pragma unroll
    for (int kk = 0; kk < 2; ++kk) {
      v8h aF[4], bF[4];
      #pragma unroll
      for (int mi = 0; mi < 4; ++mi)
        aF[mi] = *(const v8h*)(As + ((mh*4 + mi)*16 + n)*72 + kk*32 + quad*8);
      #pragma unroll
      for (int ni = 0; ni < 4; ++ni)
        bF[ni] = *(const v8h*)(Bs + ((nh*4 + ni)*16 + n)*72 + kk*32 + quad*8);
      #pragma unroll
      for (int mi = 0; mi < 4; ++mi)
        #pragma unroll
        for (int ni = 0; ni < 4; ++ni)
          acc[mi][ni] = __builtin_amdgcn_mfma_f32_16x16x32_f16(
              aF[mi], bF[ni], acc[mi][ni], 0, 0, 0);
    }
  }
  #pragma unroll
  for (int ni = 0; ni < 4; ++ni) {
    int pc0  = wgn*128 + (nh*4 + ni)*16;
    int ub   = pc0 >> 5, Tt = (pc0 >> 4) & 1;
    int gcol = (Tt*2 + (n >> 3))*512 + ub*8 + (n & 7);
    float bv = bias[gcol];
    int wg2  = bg*64 + ub;
    #pragma unroll
    for (int mi = 0; mi < 4; ++mi) {
      int t = t0 + mh*4 + mi;
      size_t off = ((((size_t)t*256 + wg2)*2 + Tt)*256) + lane*4;
      v4h o = { (h16)(acc[mi][ni][0] + bv), (h16)(acc[mi][ni][1] + bv),
                (h16)(acc[mi][ni][2] + bv), (h16)(acc[mi][ni][3] + bv) };
      *(v4h*)(xp + off) = o;
    }
  }
}

// ---------------------------------------------------------------------------
// Phase 2: persistent scan. 256 single-wave WGs; wg = bg*64 + ub.
// 4 independent groups (one per 16-row batch group) of 64 WGs each.
// Sync: per-producer epoch flags + relaxed agent atomics (no cache-wide
// wbl2/inv: all cross-WG data moves via sc0/sc1 LLC-coherent accesses).
// ---------------------------------------------------------------------------
__device__ __forceinline__ float fsig(float x) {
  return __builtin_amdgcn_rcpf(1.f + __expf(-x));
}
__device__ __forceinline__ float ftanh(float x) {
  return 1.f - 2.f * __builtin_amdgcn_rcpf(__expf(2.f*x) + 1.f);
}

__global__ __launch_bounds__(64, 1) void scan_kernel(
    const float* __restrict__ Wh, const h16* __restrict__ xp,
    h16* __restrict__ hbuf, unsigned* __restrict__ flags,
    float* __restrict__ out)
{
  const int wg   = blockIdx.x;          // 0..255
  const int lane = threadIdx.x;         // 0..63
  const int bg   = wg >> 6, ub = wg & 63;
  const int r0   = bg*16,  u0 = ub*8;
  const int n    = lane & 15, quad = lane >> 4;

  __shared__ float gbuf[16*33];         // [row r][32 gate-cols], pad 33

  // persistent B fragments: tile0 = gates {i,f}, tile1 = {g,o}
  v8h bF0[16], bF1[16];
  {
    const int g01 = n >> 3;
    const int uc  = u0 + (n & 7);
    #pragma unroll
    for (int kk = 0; kk < 16; ++kk) {
      const int kb = kk*32 + quad*8;
      v8h f0, f1;
      #pragma unroll
      for (int j = 0; j < 8; ++j) {
        f0[j] = (h16)Wh[(size_t)(kb + j)*G4 + (g01*512 + uc)];
        f1[j] = (h16)Wh[(size_t)(kb + j)*G4 + ((2 + g01)*512 + uc)];
      }
      bF0[kk] = f0; bF1[kk] = f1;
    }
  }

  float c0 = 0.f, c1 = 0.f, hf0 = 0.f, hf1 = 0.f;
  unsigned* gflags = flags + bg*64;     // this group's 64 flags (4B apart)
  unsigned* myflag = gflags + ub;

  // preload first xp fragment
  size_t xoff = ((size_t)wg*2)*256 + lane*4;
  v4h x0 = *(const v4h*)(xp + xoff);
  v4h x1 = *(const v4h*)(xp + xoff + 256);

  for (int t = 0; t < T_DIM; ++t) {
    const int p = t & 1;

    if (t) {
      const unsigned target = (unsigned)t;
      for (;;) {
        unsigned v = __hip_atomic_load(gflags + lane, __ATOMIC_RELAXED,
                                       __HIP_MEMORY_SCOPE_AGENT);
        if (__all((int)(v >= target))) break;
        __builtin_amdgcn_s_sleep(1);
      }
      asm volatile("" ::: "memory");    // no buffer_inv: h loads are coherent
    }

    // h fragment loads: LLC-coherent 8B atomic loads, all in flight
    u64* hb = (u64*)(hbuf + (size_t)p*HSZ + (size_t)(r0 + n)*H_DIM + quad*8);
    u64 hq[32];
    #pragma unroll
    for (int kk = 0; kk < 16; ++kk) {
      hq[2*kk]   = __hip_atomic_load(hb + kk*8,     __ATOMIC_RELAXED,
                                     __HIP_MEMORY_SCOPE_AGENT);
      hq[2*kk+1] = __hip_atomic_load(hb + kk*8 + 1, __ATOMIC_RELAXED,
                                     __HIP_MEMORY_SCOPE_AGENT);
    }

    // prefetch next step's xp during compute
    v4h nx0 = x0, nx1 = x1;
    if (t + 1 < T_DIM) {
      size_t nxo = (((size_t)(t+1)*256 + wg)*2)*256 + lane*4;
      nx0 = *(const v4h*)(xp + nxo);
      nx1 = *(const v4h*)(xp + nxo + 256);
    }

    v4f acc0 = { (float)x0[0], (float)x0[1], (float)x0[2], (float)x0[3] };
    v4f acc1 = { (float)x1[0], (float)x1[1], (float)x1[2], (float)x1[3] };
    v4f acc2 = { 0.f, 0.f, 0.f, 0.f };
    v4f acc3 = { 0.f, 0.f, 0.f, 0.f };
    #pragma unroll
    for (int kk = 0; kk < 8; ++kk) {
      union { u64 q[2]; v8h v; } ua, ub_;
      ua.q[0]  = hq[2*kk];      ua.q[1]  = hq[2*kk+1];
      ub_.q[0] = hq[2*(kk+8)];  ub_.q[1] = hq[2*(kk+8)+1];
      acc0 = __builtin_amdgcn_mfma_f32_16x16x32_f16(ua.v,  bF0[kk],   acc0, 0,0,0);
      acc1 = __builtin_amdgcn_mfma_f32_16x16x32_f16(ua.v,  bF1[kk],   acc1, 0,0,0);
      acc2 = __builtin_amdgcn_mfma_f32_16x16x32_f16(ub_.v, bF0[kk+8], acc2, 0,0,0);
      acc3 = __builtin_amdgcn_mfma_f32_16x16x32_f16(ub_.v, bF1[kk+8], acc3, 0,0,0);
    }
    acc0 += acc2; acc1 += acc3;

    // gate exchange: C/D layout col=lane&15, row=quad*4+reg
    #pragma unroll
    for (int r = 0; r < 4; ++r) {
      const int row = quad*4 + r;
      gbuf[row*33 + n]      = acc0[r];   // gates 0,1 (cols 0..15)
      gbuf[row*33 + 16 + n] = acc1[r];   // gates 2,3 (cols 16..31)
    }
    __syncthreads();
    const float* gr = gbuf + n*33;       // this lane's row r = n
    const int ua2 = quad*2;              // local units ua2, ua2+1
    float gi0 = gr[ua2],   gf0 = gr[8+ua2], gg0 = gr[16+ua2], go0 = gr[24+ua2];
    float gi1 = gr[ua2+1], gf1 = gr[9+ua2], gg1 = gr[17+ua2], go1 = gr[25+ua2];
    __syncthreads();                     // reads done before next-iter writes

    gi0 = fsig(gi0); gf0 = fsig(gf0); gg0 = ftanh(gg0); go0 = fsig(go0);
    gi1 = fsig(gi1); gf1 = fsig(gf1); gg1 = ftanh(gg1); go1 = fsig(go1);
    c0 = gf0*c0 + gi0*gg0;  hf0 = go0*ftanh(c0);
    c1 = gf1*c1 + gi1*gg1;  hf1 = go1*ftanh(c1);

    // coherent h store (write-through to LLC)
    union { v2h v; unsigned u; } pw;
    pw.v = (v2h){ (h16)hf0, (h16)hf1 };
    unsigned* hwp = (unsigned*)(hbuf + (size_t)(p^1)*HSZ
                                + (size_t)(r0 + n)*H_DIM + u0 + quad*2);
    __hip_atomic_store(hwp, pw.u, __ATOMIC_RELAXED, __HIP_MEMORY_SCOPE_AGENT);

    if (t < T_DIM - 1) {
      asm volatile("" ::: "memory");
      __builtin_amdgcn_s_waitcnt(0);     // drain h stores (+ xp prefetch)
      if (lane == 0)
        __hip_atomic_store(myflag, (unsigned)(t + 1), __ATOMIC_RELAXED,
                           __HIP_MEMORY_SCOPE_AGENT);
      asm volatile("" ::: "memory");
    }
    x0 = nx0; x1 = nx1;
  }
  // final carry: out[0:32768] = c, out[32768:65536] = h  (fp32)
  float* oc = out + (size_t)(r0 + n)*H_DIM + u0 + quad*2;
  oc[0] = c0; oc[1] = c1;
  oc[HSZ + 0] = hf0; oc[HSZ + 1] = hf1;
}

extern "C" void kernel_launch(void* const* d_in, const int* in_sizes, int n_in,
                              void* d_out, int out_size, void* d_ws, size_t ws_size,
                              hipStream_t stream) {
  const float* X    = (const float*)d_in[0];
  const float* Wx   = (const float*)d_in[1];
  const float* Wh   = (const float*)d_in[2];
  const float* bias = (const float*)d_in[3];
  float* out = (float*)d_out;

  char* ws = (char*)d_ws;
  h16*      xp    = (h16*)ws;
  h16*      hbuf  = (h16*)(ws + XP_BYTES);
  unsigned* flags = (unsigned*)(ws + XP_BYTES + HB_BYTES);

  // zero h double-buffer + epoch flags (ws is poisoned 0xAA each call)
  hipMemsetAsync(ws + XP_BYTES, 0, HB_BYTES + FLG_BYTES, stream);

  xproj_kernel<<<8192, 256, 0, stream>>>(X, Wx, bias, xp);
  scan_kernel<<<256, 64, 0, stream>>>(Wh, xp, hbuf, flags, out);
}

// Round 3
// 5621.713 us; speedup vs baseline: 2.6734x; 1.0042x over previous
//
#include <hip/hip_runtime.h>
#include <hip/hip_fp16.h>

#define T_DIM 1024
#define B_DIM 64
#define F_DIM 512
#define H_DIM 512
#define G4    2048
#define HSZ   (B_DIM*H_DIM)   // 32768

typedef _Float16 h16;
typedef unsigned long long u64;
typedef _Float16 v8h __attribute__((ext_vector_type(8)));
typedef _Float16 v4h __attribute__((ext_vector_type(4)));
typedef _Float16 v2h __attribute__((ext_vector_type(2)));
typedef float    v4f __attribute__((ext_vector_type(4)));

// workspace layout (bytes):
//   [0, 256MB)          xp arranged: h16 [T][256 wg][2 tile][64 lane][4 reg]
//   [+0, +256KB)        hbuf: u64 [2][64 row][256 word]  word={hi:epoch, lo:2xh16}
#define XP_HALVES ((size_t)T_DIM * 256 * 2 * 64 * 4)
#define XP_BYTES  (XP_HALVES * 2)
#define HB_WORDS  ((size_t)2 * 64 * 256)
#define HB_BYTES  (HB_WORDS * 8)       // 256 KB

// ---------------------------------------------------------------------------
// Phase 1: x_proj = X @ Wx + b, stored as fp16 in MFMA C/D fragment layout.
// ---------------------------------------------------------------------------
__global__ __launch_bounds__(256) void xproj_kernel(
    const float* __restrict__ X, const float* __restrict__ Wx,
    const float* __restrict__ bias, h16* __restrict__ xp)
{
  __shared__ __align__(16) h16 As[128*72];   // [m 0..127][k 0..63], pad 72
  __shared__ __align__(16) h16 Bs[128*72];   // [pc 0..127][k 0..63], pad 72
  const int wgid = blockIdx.x;               // 8192 blocks
  const int wgn  = wgid & 15;                // Wx-column block (128 pc)
  const int bg   = (wgid >> 4) & 3;          // batch group (16 rows)
  const int t0   = (wgid >> 6) * 8;          // 8 consecutive t per WG
  const int tid  = threadIdx.x;
  const int lane = tid & 63;
  const int wv   = tid >> 6;
  const int mh   = wv & 1, nh = wv >> 1;
  const int n    = lane & 15, quad = lane >> 4;

  v4f acc[4][4];
  #pragma unroll
  for (int mi = 0; mi < 4; ++mi)
    #pragma unroll
    for (int ni = 0; ni < 4; ++ni) acc[mi][ni] = {0.f, 0.f, 0.f, 0.f};

  for (int kc = 0; kc < 8; ++kc) {
    __syncthreads();
    {
      const int am  = tid >> 1;
      const int ak0 = (tid & 1) * 32;
      const int abl = am & 15, atl = am >> 4;
      const float* asrc = X + (((size_t)(bg*16 + abl))*T_DIM + (t0 + atl))*F_DIM
                            + kc*64 + ak0;
      h16* adst = As + am*72 + ak0;
      #pragma unroll
      for (int j = 0; j < 32; j += 4) {
        float4 v = *(const float4*)(asrc + j);
        v4h w = { (h16)v.x, (h16)v.y, (h16)v.z, (h16)v.w };
        *(v4h*)(adst + j) = w;
      }
    }
    #pragma unroll
    for (int it = 0; it < 16; ++it) {
      int idx = it*256 + tid;
      int pc  = idx & 127;
      int kp  = idx >> 7;
      int pcg = wgn*128 + pc;
      int ub  = pcg >> 5, Tt = (pcg >> 4) & 1, nn = pcg & 15;
      int gcol = (Tt*2 + (nn >> 3))*512 + ub*8 + (nn & 7);
      const float* wsrc = Wx + (size_t)(kc*64 + kp*2)*G4 + gcol;
      v2h w = { (h16)wsrc[0], (h16)wsrc[G4] };
      *(v2h*)(Bs + pc*72 + kp*2) = w;
    }
    __syncthreads();
    #pragma unroll
    for (int kk = 0; kk < 2; ++kk) {
      v8h aF[4], bF[4];
      #pragma unroll
      for (int mi = 0; mi < 4; ++mi)
        aF[mi] = *(const v8h*)(As + ((mh*4 + mi)*16 + n)*72 + kk*32 + quad*8);
      #pragma unroll
      for (int ni = 0; ni < 4; ++ni)
        bF[ni] = *(const v8h*)(Bs + ((nh*4 + ni)*16 + n)*72 + kk*32 + quad*8);
      #pragma unroll
      for (int mi = 0; mi < 4; ++mi)
        #pragma unroll
        for (int ni = 0; ni < 4; ++ni)
          acc[mi][ni] = __builtin_amdgcn_mfma_f32_16x16x32_f16(
              aF[mi], bF[ni], acc[mi][ni], 0, 0, 0);
    }
  }
  #pragma unroll
  for (int ni = 0; ni < 4; ++ni) {
    int pc0  = wgn*128 + (nh*4 + ni)*16;
    int ub   = pc0 >> 5, Tt = (pc0 >> 4) & 1;
    int gcol = (Tt*2 + (n >> 3))*512 + ub*8 + (n & 7);
    float bv = bias[gcol];
    int wg2  = bg*64 + ub;
    #pragma unroll
    for (int mi = 0; mi < 4; ++mi) {
      int t = t0 + mh*4 + mi;
      size_t off = ((((size_t)t*256 + wg2)*2 + Tt)*256) + lane*4;
      v4h o = { (h16)(acc[mi][ni][0] + bv), (h16)(acc[mi][ni][1] + bv),
                (h16)(acc[mi][ni][2] + bv), (h16)(acc[mi][ni][3] + bv) };
      *(v4h*)(xp + off) = o;
    }
  }
}

// ---------------------------------------------------------------------------
// Phase 2: persistent scan. 256 single-wave WGs; wg = bg*64 + ub.
// 4 independent groups (one per 16-row batch group) of 64 WGs each.
// Sync: SELF-VALIDATING h words. Each u64 = {hi: epoch tag, lo: 2 fp16 h}.
// Producer: one relaxed-agent 8B store per lane (tag t+1), no drain, no flag.
// Consumer: poll the 64 words it needs until all tags == t; the lo dwords
// are directly the MFMA A-fragment data. One LLC RTT per poll iteration.
// ---------------------------------------------------------------------------
__device__ __forceinline__ float fsig(float x) {
  return __builtin_amdgcn_rcpf(1.f + __expf(-x));
}
__device__ __forceinline__ float ftanh(float x) {
  return 1.f - 2.f * __builtin_amdgcn_rcpf(__expf(2.f*x) + 1.f);
}

__global__ __launch_bounds__(64, 1) void scan_kernel(
    const float* __restrict__ Wh, const h16* __restrict__ xp,
    u64* __restrict__ hbuf, float* __restrict__ out)
{
  const int wg   = blockIdx.x;          // 0..255
  const int lane = threadIdx.x;         // 0..63
  const int bg   = wg >> 6, ub = wg & 63;
  const int r0   = bg*16,  u0 = ub*8;
  const int n    = lane & 15, quad = lane >> 4;

  __shared__ float gbuf[16*33];         // [row r][32 gate-cols], pad 33

  // persistent B fragments: tile0 = gates {i,f}, tile1 = {g,o}
  v8h bF0[16], bF1[16];
  {
    const int g01 = n >> 3;
    const int uc  = u0 + (n & 7);
    #pragma unroll
    for (int kk = 0; kk < 16; ++kk) {
      const int kb = kk*32 + quad*8;
      v8h f0, f1;
      #pragma unroll
      for (int j = 0; j < 8; ++j) {
        f0[j] = (h16)Wh[(size_t)(kb + j)*G4 + (g01*512 + uc)];
        f1[j] = (h16)Wh[(size_t)(kb + j)*G4 + ((2 + g01)*512 + uc)];
      }
      bF0[kk] = f0; bF1[kk] = f1;
    }
  }

  float c0 = 0.f, c1 = 0.f, hf0 = 0.f, hf1 = 0.f;

  // preload first xp fragment
  size_t xoff = ((size_t)wg*2)*256 + lane*4;
  v4h x0 = *(const v4h*)(xp + xoff);
  v4h x1 = *(const v4h*)(xp + xoff + 256);

  for (int t = 0; t < T_DIM; ++t) {
    const int p = t & 1;

    // self-validating poll: 64 tagged u64 words = this lane's 16 A-fragments
    // word layout per row: 256 u64 (512 units / 2). Fragment kk needs words
    // [kk*16 + quad*4 .. +3] of row r0+n.
    const u64* hb = hbuf + (size_t)p*16384 + (size_t)(r0 + n)*256 + quad*4;
    u64 w[64];
    {
      const unsigned target = (unsigned)t;
      for (;;) {
        #pragma unroll
        for (int kk = 0; kk < 16; ++kk)
          #pragma unroll
          for (int i = 0; i < 4; ++i)
            w[kk*4 + i] = __hip_atomic_load(hb + kk*16 + i, __ATOMIC_RELAXED,
                                            __HIP_MEMORY_SCOPE_AGENT);
        bool ok = true;
        #pragma unroll
        for (int j = 0; j < 64; ++j)
          ok &= ((unsigned)(w[j] >> 32) == target);
        if (__all((int)ok)) break;
        __builtin_amdgcn_s_sleep(1);
      }
    }

    // prefetch next step's xp during compute
    v4h nx0 = x0, nx1 = x1;
    if (t + 1 < T_DIM) {
      size_t nxo = (((size_t)(t+1)*256 + wg)*2)*256 + lane*4;
      nx0 = *(const v4h*)(xp + nxo);
      nx1 = *(const v4h*)(xp + nxo + 256);
    }

    v4f acc0 = { (float)x0[0], (float)x0[1], (float)x0[2], (float)x0[3] };
    v4f acc1 = { (float)x1[0], (float)x1[1], (float)x1[2], (float)x1[3] };
    v4f acc2 = { 0.f, 0.f, 0.f, 0.f };
    v4f acc3 = { 0.f, 0.f, 0.f, 0.f };
    #pragma unroll
    for (int kk = 0; kk < 8; ++kk) {
      union { unsigned d[4]; v8h v; } a0, a1;
      #pragma unroll
      for (int i = 0; i < 4; ++i) {
        a0.d[i] = (unsigned)w[kk*4 + i];
        a1.d[i] = (unsigned)w[(kk+8)*4 + i];
      }
      acc0 = __builtin_amdgcn_mfma_f32_16x16x32_f16(a0.v, bF0[kk],   acc0, 0,0,0);
      acc1 = __builtin_amdgcn_mfma_f32_16x16x32_f16(a0.v, bF1[kk],   acc1, 0,0,0);
      acc2 = __builtin_amdgcn_mfma_f32_16x16x32_f16(a1.v, bF0[kk+8], acc2, 0,0,0);
      acc3 = __builtin_amdgcn_mfma_f32_16x16x32_f16(a1.v, bF1[kk+8], acc3, 0,0,0);
    }
    acc0 += acc2; acc1 += acc3;

    // gate exchange: C/D layout col=lane&15, row=quad*4+reg
    #pragma unroll
    for (int r = 0; r < 4; ++r) {
      const int row = quad*4 + r;
      gbuf[row*33 + n]      = acc0[r];   // gates 0,1 (cols 0..15)
      gbuf[row*33 + 16 + n] = acc1[r];   // gates 2,3 (cols 16..31)
    }
    __syncthreads();
    const float* gr = gbuf + n*33;       // this lane's row r = n
    const int ua2 = quad*2;              // local units ua2, ua2+1
    float gi0 = gr[ua2],   gf0 = gr[8+ua2], gg0 = gr[16+ua2], go0 = gr[24+ua2];
    float gi1 = gr[ua2+1], gf1 = gr[9+ua2], gg1 = gr[17+ua2], go1 = gr[25+ua2];
    __syncthreads();                     // reads done before next-iter writes

    gi0 = fsig(gi0); gf0 = fsig(gf0); gg0 = ftanh(gg0); go0 = fsig(go0);
    gi1 = fsig(gi1); gf1 = fsig(gf1); gg1 = ftanh(gg1); go1 = fsig(go1);
    c0 = gf0*c0 + gi0*gg0;  hf0 = go0*ftanh(c0);
    c1 = gf1*c1 + gi1*gg1;  hf1 = go1*ftanh(c1);

    // tagged h store: {hi: t+1, lo: 2 fp16} — single 8B relaxed agent store
    if (t < T_DIM - 1) {
      union { v2h v; unsigned u; } pw;
      pw.v = (v2h){ (h16)hf0, (h16)hf1 };
      u64 word = ((u64)(unsigned)(t + 1) << 32) | (u64)pw.u;
      u64* hwp = hbuf + (size_t)(p^1)*16384 + (size_t)(r0 + n)*256 + ub*4 + quad;
      __hip_atomic_store(hwp, word, __ATOMIC_RELAXED, __HIP_MEMORY_SCOPE_AGENT);
    }
    x0 = nx0; x1 = nx1;
  }
  // final carry: out[0:32768] = c, out[32768:65536] = h  (fp32)
  float* oc = out + (size_t)(r0 + n)*H_DIM + u0 + quad*2;
  oc[0] = c0; oc[1] = c1;
  oc[HSZ + 0] = hf0; oc[HSZ + 1] = hf1;
}

extern "C" void kernel_launch(void* const* d_in, const int* in_sizes, int n_in,
                              void* d_out, int out_size, void* d_ws, size_t ws_size,
                              hipStream_t stream) {
  const float* X    = (const float*)d_in[0];
  const float* Wx   = (const float*)d_in[1];
  const float* Wh   = (const float*)d_in[2];
  const float* bias = (const float*)d_in[3];
  float* out = (float*)d_out;

  char* ws = (char*)d_ws;
  h16* xp   = (h16*)ws;
  u64* hbuf = (u64*)(ws + XP_BYTES);

  // zero hbuf (tags -> 0 == t=0 target, h -> 0.0); ws is poisoned 0xAA
  hipMemsetAsync(ws + XP_BYTES, 0, HB_BYTES, stream);

  xproj_kernel<<<8192, 256, 0, stream>>>(X, Wx, bias, xp);
  scan_kernel<<<256, 64, 0, stream>>>(Wh, xp, hbuf, out);
}

// Round 4
// 4285.593 us; speedup vs baseline: 3.5069x; 1.3118x over previous
//
#include <hip/hip_runtime.h>
#include <hip/hip_fp16.h>

#define T_DIM 1024
#define B_DIM 64
#define F_DIM 512
#define H_DIM 512
#define G4    2048
#define HSZ   (B_DIM*H_DIM)   // 32768

typedef _Float16 h16;
typedef unsigned long long u64;
typedef _Float16 v8h __attribute__((ext_vector_type(8)));
typedef _Float16 v4h __attribute__((ext_vector_type(4)));
typedef _Float16 v2h __attribute__((ext_vector_type(2)));
typedef float    v4f __attribute__((ext_vector_type(4)));

// workspace layout (bytes):
//   [0, 256MB)          xp arranged: h16 [T][256 wg][2 tile][64 lane][4 reg]
//   [+0, +256KB)        hbuf: u64 [2 phase][4 group][64 j][64 lane]
//                       word={hi:epoch tag, lo:2xh16}, consumer-contiguous
#define XP_HALVES ((size_t)T_DIM * 256 * 2 * 64 * 4)
#define XP_BYTES  (XP_HALVES * 2)
#define HB_WORDS  ((size_t)2 * 4 * 64 * 64)
#define HB_BYTES  (HB_WORDS * 8)       // 256 KB

// ---------------------------------------------------------------------------
// Phase 1: x_proj = X @ Wx + b, stored as fp16 in MFMA C/D fragment layout.
// ---------------------------------------------------------------------------
__global__ __launch_bounds__(256) void xproj_kernel(
    const float* __restrict__ X, const float* __restrict__ Wx,
    const float* __restrict__ bias, h16* __restrict__ xp)
{
  __shared__ __align__(16) h16 As[128*72];   // [m 0..127][k 0..63], pad 72
  __shared__ __align__(16) h16 Bs[128*72];   // [pc 0..127][k 0..63], pad 72
  const int wgid = blockIdx.x;               // 8192 blocks
  const int wgn  = wgid & 15;                // Wx-column block (128 pc)
  const int bg   = (wgid >> 4) & 3;          // batch group (16 rows)
  const int t0   = (wgid >> 6) * 8;          // 8 consecutive t per WG
  const int tid  = threadIdx.x;
  const int lane = tid & 63;
  const int wv   = tid >> 6;
  const int mh   = wv & 1, nh = wv >> 1;
  const int n    = lane & 15, quad = lane >> 4;

  v4f acc[4][4];
  #pragma unroll
  for (int mi = 0; mi < 4; ++mi)
    #pragma unroll
    for (int ni = 0; ni < 4; ++ni) acc[mi][ni] = {0.f, 0.f, 0.f, 0.f};

  for (int kc = 0; kc < 8; ++kc) {
    __syncthreads();
    {
      const int am  = tid >> 1;
      const int ak0 = (tid & 1) * 32;
      const int abl = am & 15, atl = am >> 4;
      const float* asrc = X + (((size_t)(bg*16 + abl))*T_DIM + (t0 + atl))*F_DIM
                            + kc*64 + ak0;
      h16* adst = As + am*72 + ak0;
      #pragma unroll
      for (int j = 0; j < 32; j += 4) {
        float4 v = *(const float4*)(asrc + j);
        v4h w = { (h16)v.x, (h16)v.y, (h16)v.z, (h16)v.w };
        *(v4h*)(adst + j) = w;
      }
    }
    #pragma unroll
    for (int it = 0; it < 16; ++it) {
      int idx = it*256 + tid;
      int pc  = idx & 127;
      int kp  = idx >> 7;
      int pcg = wgn*128 + pc;
      int ub  = pcg >> 5, Tt = (pcg >> 4) & 1, nn = pcg & 15;
      int gcol = (Tt*2 + (nn >> 3))*512 + ub*8 + (nn & 7);
      const float* wsrc = Wx + (size_t)(kc*64 + kp*2)*G4 + gcol;
      v2h w = { (h16)wsrc[0], (h16)wsrc[G4] };
      *(v2h*)(Bs + pc*72 + kp*2) = w;
    }
    __syncthreads();
    #pragma unroll
    for (int kk = 0; kk < 2; ++kk) {
      v8h aF[4], bF[4];
      #pragma unroll
      for (int mi = 0; mi < 4; ++mi)
        aF[mi] = *(const v8h*)(As + ((mh*4 + mi)*16 + n)*72 + kk*32 + quad*8);
      #pragma unroll
      for (int ni = 0; ni < 4; ++ni)
        bF[ni] = *(const v8h*)(Bs + ((nh*4 + ni)*16 + n)*72 + kk*32 + quad*8);
      #pragma unroll
      for (int mi = 0; mi < 4; ++mi)
        #pragma unroll
        for (int ni = 0; ni < 4; ++ni)
          acc[mi][ni] = __builtin_amdgcn_mfma_f32_16x16x32_f16(
              aF[mi], bF[ni], acc[mi][ni], 0, 0, 0);
    }
  }
  #pragma unroll
  for (int ni = 0; ni < 4; ++ni) {
    int pc0  = wgn*128 + (nh*4 + ni)*16;
    int ub   = pc0 >> 5, Tt = (pc0 >> 4) & 1;
    int gcol = (Tt*2 + (n >> 3))*512 + ub*8 + (n & 7);
    float bv = bias[gcol];
    int wg2  = bg*64 + ub;
    #pragma unroll
    for (int mi = 0; mi < 4; ++mi) {
      int t = t0 + mh*4 + mi;
      size_t off = ((((size_t)t*256 + wg2)*2 + Tt)*256) + lane*4;
      v4h o = { (h16)(acc[mi][ni][0] + bv), (h16)(acc[mi][ni][1] + bv),
                (h16)(acc[mi][ni][2] + bv), (h16)(acc[mi][ni][3] + bv) };
      *(v4h*)(xp + off) = o;
    }
  }
}

// ---------------------------------------------------------------------------
// Phase 2: persistent scan. 256 single-wave WGs; wg = bg*64 + ub.
// 4 independent groups (16 batch rows each) of 64 WGs.
// Self-validating tagged h words, CONSUMER-CONTIGUOUS layout:
//   word index within [phase][group] buffer = j*64 + lane, j = kk*4 + i.
// Consumer instr j reads 512 B contiguous; producer's one store per lane
// lands as 4 fully-written 128 B chunks. Zero cacheline amplification.
// ---------------------------------------------------------------------------
__device__ __forceinline__ float fsig(float x) {
  return __builtin_amdgcn_rcpf(1.f + __expf(-x));
}
__device__ __forceinline__ float ftanh(float x) {
  return 1.f - 2.f * __builtin_amdgcn_rcpf(__expf(2.f*x) + 1.f);
}

__global__ __launch_bounds__(64, 1) void scan_kernel(
    const float* __restrict__ Wh, const h16* __restrict__ xp,
    u64* __restrict__ hbuf, float* __restrict__ out)
{
  const int wg   = blockIdx.x;          // 0..255
  const int lane = threadIdx.x;         // 0..63
  const int bg   = wg >> 6, ub = wg & 63;
  const int r0   = bg*16,  u0 = ub*8;
  const int n    = lane & 15, quad = lane >> 4;

  __shared__ float gbuf[16*33];         // [row r][32 gate-cols], pad 33

  // persistent B fragments: tile0 = gates {i,f}, tile1 = {g,o}
  v8h bF0[16], bF1[16];
  {
    const int g01 = n >> 3;
    const int uc  = u0 + (n & 7);
    #pragma unroll
    for (int kk = 0; kk < 16; ++kk) {
      const int kb = kk*32 + quad*8;
      v8h f0, f1;
      #pragma unroll
      for (int j = 0; j < 8; ++j) {
        f0[j] = (h16)Wh[(size_t)(kb + j)*G4 + (g01*512 + uc)];
        f1[j] = (h16)Wh[(size_t)(kb + j)*G4 + ((2 + g01)*512 + uc)];
      }
      bF0[kk] = f0; bF1[kk] = f1;
    }
  }

  float c0 = 0.f, c1 = 0.f, hf0 = 0.f, hf1 = 0.f;

  // producer store slot (consumer-contiguous layout):
  // offset = ((ub>>2)*4 + quad)*64 + (ub&3)*16 + n
  const int pslot = ((ub >> 2)*4 + quad)*64 + (ub & 3)*16 + n;

  // preload first xp fragment
  size_t xoff = ((size_t)wg*2)*256 + lane*4;
  v4h x0 = *(const v4h*)(xp + xoff);
  v4h x1 = *(const v4h*)(xp + xoff + 256);

  for (int t = 0; t < T_DIM; ++t) {
    const int p = t & 1;

    // prefetch next step's xp first: HBM latency hides under the poll
    v4h nx0 = x0, nx1 = x1;
    if (t + 1 < T_DIM) {
      size_t nxo = (((size_t)(t+1)*256 + wg)*2)*256 + lane*4;
      nx0 = *(const v4h*)(xp + nxo);
      nx1 = *(const v4h*)(xp + nxo + 256);
    }

    // self-validating poll: instr j loads word j*64+lane (512 B contiguous)
    const u64* hb = hbuf + ((size_t)p*4 + bg)*4096 + lane;
    u64 w[64];
    {
      const unsigned target = (unsigned)t;
      for (;;) {
        #pragma unroll
        for (int j = 0; j < 64; ++j)
          w[j] = __hip_atomic_load(hb + j*64, __ATOMIC_RELAXED,
                                   __HIP_MEMORY_SCOPE_AGENT);
        unsigned bad = 0;
        #pragma unroll
        for (int j = 0; j < 64; ++j)
          bad |= ((unsigned)(w[j] >> 32)) ^ target;
        if (__all((int)(bad == 0))) break;
        __builtin_amdgcn_s_sleep(1);
      }
    }

    v4f acc0 = { (float)x0[0], (float)x0[1], (float)x0[2], (float)x0[3] };
    v4f acc1 = { (float)x1[0], (float)x1[1], (float)x1[2], (float)x1[3] };
    v4f acc2 = { 0.f, 0.f, 0.f, 0.f };
    v4f acc3 = { 0.f, 0.f, 0.f, 0.f };
    #pragma unroll
    for (int kk = 0; kk < 8; ++kk) {
      union { unsigned d[4]; v8h v; } a0, a1;
      #pragma unroll
      for (int i = 0; i < 4; ++i) {
        a0.d[i] = (unsigned)w[kk*4 + i];
        a1.d[i] = (unsigned)w[(kk+8)*4 + i];
      }
      acc0 = __builtin_amdgcn_mfma_f32_16x16x32_f16(a0.v, bF0[kk],   acc0, 0,0,0);
      acc1 = __builtin_amdgcn_mfma_f32_16x16x32_f16(a0.v, bF1[kk],   acc1, 0,0,0);
      acc2 = __builtin_amdgcn_mfma_f32_16x16x32_f16(a1.v, bF0[kk+8], acc2, 0,0,0);
      acc3 = __builtin_amdgcn_mfma_f32_16x16x32_f16(a1.v, bF1[kk+8], acc3, 0,0,0);
    }
    acc0 += acc2; acc1 += acc3;

    // gate exchange: C/D layout col=lane&15, row=quad*4+reg
    #pragma unroll
    for (int r = 0; r < 4; ++r) {
      const int row = quad*4 + r;
      gbuf[row*33 + n]      = acc0[r];   // gates 0,1 (cols 0..15)
      gbuf[row*33 + 16 + n] = acc1[r];   // gates 2,3 (cols 16..31)
    }
    __syncthreads();
    const float* gr = gbuf + n*33;       // this lane's row r = n
    const int ua2 = quad*2;              // local units ua2, ua2+1
    float gi0 = gr[ua2],   gf0 = gr[8+ua2], gg0 = gr[16+ua2], go0 = gr[24+ua2];
    float gi1 = gr[ua2+1], gf1 = gr[9+ua2], gg1 = gr[17+ua2], go1 = gr[25+ua2];
    __syncthreads();                     // reads done before next-iter writes

    gi0 = fsig(gi0); gf0 = fsig(gf0); gg0 = ftanh(gg0); go0 = fsig(go0);
    gi1 = fsig(gi1); gf1 = fsig(gf1); gg1 = ftanh(gg1); go1 = fsig(go1);
    c0 = gf0*c0 + gi0*gg0;  hf0 = go0*ftanh(c0);
    c1 = gf1*c1 + gi1*gg1;  hf1 = go1*ftanh(c1);

    // tagged h store: {hi: t+1, lo: 2 fp16} — single 8B relaxed agent store
    if (t < T_DIM - 1) {
      union { v2h v; unsigned u; } pw;
      pw.v = (v2h){ (h16)hf0, (h16)hf1 };
      u64 word = ((u64)(unsigned)(t + 1) << 32) | (u64)pw.u;
      u64* hwp = hbuf + ((size_t)(p^1)*4 + bg)*4096 + pslot;
      __hip_atomic_store(hwp, word, __ATOMIC_RELAXED, __HIP_MEMORY_SCOPE_AGENT);
    }
    x0 = nx0; x1 = nx1;
  }
  // final carry: out[0:32768] = c, out[32768:65536] = h  (fp32)
  float* oc = out + (size_t)(r0 + n)*H_DIM + u0 + quad*2;
  oc[0] = c0; oc[1] = c1;
  oc[HSZ + 0] = hf0; oc[HSZ + 1] = hf1;
}

extern "C" void kernel_launch(void* const* d_in, const int* in_sizes, int n_in,
                              void* d_out, int out_size, void* d_ws, size_t ws_size,
                              hipStream_t stream) {
  const float* X    = (const float*)d_in[0];
  const float* Wx   = (const float*)d_in[1];
  const float* Wh   = (const float*)d_in[2];
  const float* bias = (const float*)d_in[3];
  float* out = (float*)d_out;

  char* ws = (char*)d_ws;
  h16* xp   = (h16*)ws;
  u64* hbuf = (u64*)(ws + XP_BYTES);

  // zero hbuf (tags -> 0 == t=0 target, h -> 0.0); ws is poisoned 0xAA
  hipMemsetAsync(ws + XP_BYTES, 0, HB_BYTES, stream);

  xproj_kernel<<<8192, 256, 0, stream>>>(X, Wx, bias, xp);
  scan_kernel<<<256, 64, 0, stream>>>(Wh, xp, hbuf, out);
}

// Round 5
// 3217.652 us; speedup vs baseline: 4.6708x; 1.3319x over previous
//
#include <hip/hip_runtime.h>
#include <hip/hip_fp16.h>

#define T_DIM 1024
#define B_DIM 64
#define F_DIM 512
#define H_DIM 512
#define G4    2048
#define HSZ   (B_DIM*H_DIM)   // 32768

typedef _Float16 h16;
typedef unsigned long long u64;
typedef _Float16 v8h __attribute__((ext_vector_type(8)));
typedef _Float16 v4h __attribute__((ext_vector_type(4)));
typedef _Float16 v2h __attribute__((ext_vector_type(2)));
typedef float    v4f __attribute__((ext_vector_type(4)));

// workspace layout (bytes):
//   [0, 256MB)          xp arranged: h16 [T][256 wg][2 tile][64 lane][4 reg]
//   [+0, +256KB)        hbuf: u64 [2 phase][4 group][4096 word]
//                       word={hi:epoch tag, lo:2xh16}, frag-ordered:
//                       W(n, pair p) = (p>>4)*256 + ((p>>2)&3)*64 + n*4 + (p&3)
#define XP_HALVES ((size_t)T_DIM * 256 * 2 * 64 * 4)
#define XP_BYTES  (XP_HALVES * 2)
#define HB_WORDS  ((size_t)2 * 4 * 4096)
#define HB_BYTES  (HB_WORDS * 8)       // 256 KB

// ---------------------------------------------------------------------------
// Phase 1: x_proj = X @ Wx + b, stored as fp16 in MFMA C/D fragment layout.
// (unchanged from round 4)
// ---------------------------------------------------------------------------
__global__ __launch_bounds__(256) void xproj_kernel(
    const float* __restrict__ X, const float* __restrict__ Wx,
    const float* __restrict__ bias, h16* __restrict__ xp)
{
  __shared__ __align__(16) h16 As[128*72];   // [m 0..127][k 0..63], pad 72
  __shared__ __align__(16) h16 Bs[128*72];   // [pc 0..127][k 0..63], pad 72
  const int wgid = blockIdx.x;               // 8192 blocks
  const int wgn  = wgid & 15;                // Wx-column block (128 pc)
  const int bg   = (wgid >> 4) & 3;          // batch group (16 rows)
  const int t0   = (wgid >> 6) * 8;          // 8 consecutive t per WG
  const int tid  = threadIdx.x;
  const int lane = tid & 63;
  const int wv   = tid >> 6;
  const int mh   = wv & 1, nh = wv >> 1;
  const int n    = lane & 15, quad = lane >> 4;

  v4f acc[4][4];
  #pragma unroll
  for (int mi = 0; mi < 4; ++mi)
    #pragma unroll
    for (int ni = 0; ni < 4; ++ni) acc[mi][ni] = {0.f, 0.f, 0.f, 0.f};

  for (int kc = 0; kc < 8; ++kc) {
    __syncthreads();
    {
      const int am  = tid >> 1;
      const int ak0 = (tid & 1) * 32;
      const int abl = am & 15, atl = am >> 4;
      const float* asrc = X + (((size_t)(bg*16 + abl))*T_DIM + (t0 + atl))*F_DIM
                            + kc*64 + ak0;
      h16* adst = As + am*72 + ak0;
      #pragma unroll
      for (int j = 0; j < 32; j += 4) {
        float4 v = *(const float4*)(asrc + j);
        v4h w = { (h16)v.x, (h16)v.y, (h16)v.z, (h16)v.w };
        *(v4h*)(adst + j) = w;
      }
    }
    #pragma unroll
    for (int it = 0; it < 16; ++it) {
      int idx = it*256 + tid;
      int pc  = idx & 127;
      int kp  = idx >> 7;
      int pcg = wgn*128 + pc;
      int ub  = pcg >> 5, Tt = (pcg >> 4) & 1, nn = pcg & 15;
      int gcol = (Tt*2 + (nn >> 3))*512 + ub*8 + (nn & 7);
      const float* wsrc = Wx + (size_t)(kc*64 + kp*2)*G4 + gcol;
      v2h w = { (h16)wsrc[0], (h16)wsrc[G4] };
      *(v2h*)(Bs + pc*72 + kp*2) = w;
    }
    __syncthreads();
    #pragma unroll
    for (int kk = 0; kk < 2; ++kk) {
      v8h aF[4], bF[4];
      #pragma unroll
      for (int mi = 0; mi < 4; ++mi)
        aF[mi] = *(const v8h*)(As + ((mh*4 + mi)*16 + n)*72 + kk*32 + quad*8);
      #pragma unroll
      for (int ni = 0; ni < 4; ++ni)
        bF[ni] = *(const v8h*)(Bs + ((nh*4 + ni)*16 + n)*72 + kk*32 + quad*8);
      #pragma unroll
      for (int mi = 0; mi < 4; ++mi)
        #pragma unroll
        for (int ni = 0; ni < 4; ++ni)
          acc[mi][ni] = __builtin_amdgcn_mfma_f32_16x16x32_f16(
              aF[mi], bF[ni], acc[mi][ni], 0, 0, 0);
    }
  }
  #pragma unroll
  for (int ni = 0; ni < 4; ++ni) {
    int pc0  = wgn*128 + (nh*4 + ni)*16;
    int ub   = pc0 >> 5, Tt = (pc0 >> 4) & 1;
    int gcol = (Tt*2 + (n >> 3))*512 + ub*8 + (n & 7);
    float bv = bias[gcol];
    int wg2  = bg*64 + ub;
    #pragma unroll
    for (int mi = 0; mi < 4; ++mi) {
      int t = t0 + mh*4 + mi;
      size_t off = ((((size_t)t*256 + wg2)*2 + Tt)*256) + lane*4;
      v4h o = { (h16)(acc[mi][ni][0] + bv), (h16)(acc[mi][ni][1] + bv),
                (h16)(acc[mi][ni][2] + bv), (h16)(acc[mi][ni][3] + bv) };
      *(v4h*)(xp + off) = o;
    }
  }
}

// ---------------------------------------------------------------------------
// Phase 2: persistent scan. 64 WGs x 256 threads (4 waves). WG bx = g*16+w:
// group g (16 rows), unit-block w (32 units). Wave wv owns 8 units (all 4
// gates), identical per-wave structure to round 4 with ub = w*4+wv.
// Sync: tagged u64 words in frag-ordered group buffer; WG fetches its
// group's 4096 words cooperatively (16 loads/lane), validates per wave,
// redistributes payload through double-buffered LDS; all global loads,
// stores, and LDS payload writes are coalesced/conflict-free by layout.
// ---------------------------------------------------------------------------
__device__ __forceinline__ float fsig(float x) {
  return __builtin_amdgcn_rcpf(1.f + __expf(-x));
}
__device__ __forceinline__ float ftanh(float x) {
  return 1.f - 2.f * __builtin_amdgcn_rcpf(__expf(2.f*x) + 1.f);
}

__global__ __launch_bounds__(256, 1) void scan_kernel(
    const float* __restrict__ Wh, const h16* __restrict__ xp,
    u64* __restrict__ hbuf, float* __restrict__ out)
{
  const int bx   = blockIdx.x;          // 0..63
  const int g    = bx >> 4, w = bx & 15;
  const int tid  = threadIdx.x;         // 0..255
  const int wv   = tid >> 6;
  const int lane = tid & 63;
  const int n    = lane & 15, quad = lane >> 4;
  const int ub   = w*4 + wv;            // 8-unit block 0..63
  const int r0   = g*16,  u0 = ub*8;

  __shared__ unsigned hlds[2][4096];    // payload dwords, frag-ordered, dbuf
  __shared__ float gbuf[4][16*33];      // per-wave gate exchange

  // persistent B fragments: tile0 = gates {i,f}, tile1 = {g,o}
  v8h bF0[16], bF1[16];
  {
    const int g01 = n >> 3;
    const int uc  = u0 + (n & 7);
    #pragma unroll
    for (int kk = 0; kk < 16; ++kk) {
      const int kb = kk*32 + quad*8;
      v8h f0, f1;
      #pragma unroll
      for (int j = 0; j < 8; ++j) {
        f0[j] = (h16)Wh[(size_t)(kb + j)*G4 + (g01*512 + uc)];
        f1[j] = (h16)Wh[(size_t)(kb + j)*G4 + ((2 + g01)*512 + uc)];
      }
      bF0[kk] = f0; bF1[kk] = f1;
    }
  }

  float c0 = 0.f, c1 = 0.f, hf0 = 0.f, hf1 = 0.f;

  // producer slot: unit-pair p = w*16 + wv*4 + quad, row n ->
  // W = w*256 + wv*64 + n*4 + quad  (coalesced per wave instr)
  const int pslot = w*256 + wv*64 + n*4 + quad;

  // preload first xp fragment
  size_t xoff = ((size_t)(g*64 + ub)*2)*256 + lane*4;
  v4h x0 = *(const v4h*)(xp + xoff);
  v4h x1 = *(const v4h*)(xp + xoff + 256);

  for (int t = 0; t < T_DIM; ++t) {
    const int p = t & 1;

    // prefetch next step's xp first: HBM latency hides under the poll
    v4h nx0 = x0, nx1 = x1;
    if (t + 1 < T_DIM) {
      size_t nxo = (((size_t)(t+1)*256 + g*64 + ub)*2)*256 + lane*4;
      nx0 = *(const v4h*)(xp + nxo);
      nx1 = *(const v4h*)(xp + nxo + 256);
    }

    // cooperative poll: this thread owns words j*256+tid (j=0..15);
    // each wave-instr reads 512 B contiguous
    const u64* hb = hbuf + ((size_t)p*4 + g)*4096 + tid;
    u64 wq[16];
    {
      const unsigned target = (unsigned)t;
      for (;;) {
        #pragma unroll
        for (int j = 0; j < 16; ++j)
          wq[j] = __hip_atomic_load(hb + j*256, __ATOMIC_RELAXED,
                                    __HIP_MEMORY_SCOPE_AGENT);
        unsigned bad = 0;
        #pragma unroll
        for (int j = 0; j < 16; ++j)
          bad |= ((unsigned)(wq[j] >> 32)) ^ target;
        if (__all((int)(bad == 0))) break;
        __builtin_amdgcn_s_sleep(1);
      }
    }
    // redistribute payloads (conflict-free: bank = tid%32)
    {
      unsigned* hl = &hlds[p][tid];
      #pragma unroll
      for (int j = 0; j < 16; ++j) hl[j*256] = (unsigned)wq[j];
    }
    __syncthreads();

    v4f acc0 = { (float)x0[0], (float)x0[1], (float)x0[2], (float)x0[3] };
    v4f acc1 = { (float)x1[0], (float)x1[1], (float)x1[2], (float)x1[3] };
    v4f acc2 = { 0.f, 0.f, 0.f, 0.f };
    v4f acc3 = { 0.f, 0.f, 0.f, 0.f };
    const unsigned* hfr = &hlds[p][quad*64 + n*4];
    #pragma unroll
    for (int kk = 0; kk < 8; ++kk) {
      v8h a0 = *(const v8h*)(hfr + kk*256);
      v8h a1 = *(const v8h*)(hfr + (kk+8)*256);
      acc0 = __builtin_amdgcn_mfma_f32_16x16x32_f16(a0, bF0[kk],   acc0, 0,0,0);
      acc1 = __builtin_amdgcn_mfma_f32_16x16x32_f16(a0, bF1[kk],   acc1, 0,0,0);
      acc2 = __builtin_amdgcn_mfma_f32_16x16x32_f16(a1, bF0[kk+8], acc2, 0,0,0);
      acc3 = __builtin_amdgcn_mfma_f32_16x16x32_f16(a1, bF1[kk+8], acc3, 0,0,0);
    }
    acc0 += acc2; acc1 += acc3;

    // gate exchange within wave: C/D layout col=lane&15, row=quad*4+reg
    float* gb = gbuf[wv];
    #pragma unroll
    for (int r = 0; r < 4; ++r) {
      const int row = quad*4 + r;
      gb[row*33 + n]      = acc0[r];   // gates 0,1 (cols 0..15)
      gb[row*33 + 16 + n] = acc1[r];   // gates 2,3 (cols 16..31)
    }
    __builtin_amdgcn_wave_barrier();   // per-wave region: in-order LDS, no s_barrier
    const float* gr = gb + n*33;       // this lane's row r = n
    const int ua2 = quad*2;            // local units ua2, ua2+1
    float gi0 = gr[ua2],   gf0 = gr[8+ua2], gg0 = gr[16+ua2], go0 = gr[24+ua2];
    float gi1 = gr[ua2+1], gf1 = gr[9+ua2], gg1 = gr[17+ua2], go1 = gr[25+ua2];
    __builtin_amdgcn_wave_barrier();

    gi0 = fsig(gi0); gf0 = fsig(gf0); gg0 = ftanh(gg0); go0 = fsig(go0);
    gi1 = fsig(gi1); gf1 = fsig(gf1); gg1 = ftanh(gg1); go1 = fsig(go1);
    c0 = gf0*c0 + gi0*gg0;  hf0 = go0*ftanh(c0);
    c1 = gf1*c1 + gi1*gg1;  hf1 = go1*ftanh(c1);

    // tagged h store: {hi: t+1, lo: 2 fp16} — single 8B relaxed agent store
    if (t < T_DIM - 1) {
      union { v2h v; unsigned u; } pw;
      pw.v = (v2h){ (h16)hf0, (h16)hf1 };
      u64 word = ((u64)(unsigned)(t + 1) << 32) | (u64)pw.u;
      u64* hwp = hbuf + ((size_t)(p^1)*4 + g)*4096 + pslot;
      __hip_atomic_store(hwp, word, __ATOMIC_RELAXED, __HIP_MEMORY_SCOPE_AGENT);
    }
    x0 = nx0; x1 = nx1;
  }
  // final carry: out[0:32768] = c, out[32768:65536] = h  (fp32)
  float* oc = out + (size_t)(r0 + n)*H_DIM + u0 + quad*2;
  oc[0] = c0; oc[1] = c1;
  oc[HSZ + 0] = hf0; oc[HSZ + 1] = hf1;
}

extern "C" void kernel_launch(void* const* d_in, const int* in_sizes, int n_in,
                              void* d_out, int out_size, void* d_ws, size_t ws_size,
                              hipStream_t stream) {
  const float* X    = (const float*)d_in[0];
  const float* Wx   = (const float*)d_in[1];
  const float* Wh   = (const float*)d_in[2];
  const float* bias = (const float*)d_in[3];
  float* out = (float*)d_out;

  char* ws = (char*)d_ws;
  h16* xp   = (h16*)ws;
  u64* hbuf = (u64*)(ws + XP_BYTES);

  // zero hbuf (tags -> 0 == t=0 target, h -> 0.0); ws is poisoned 0xAA
  hipMemsetAsync(ws + XP_BYTES, 0, HB_BYTES, stream);

  xproj_kernel<<<8192, 256, 0, stream>>>(X, Wx, bias, xp);
  scan_kernel<<<64, 256, 0, stream>>>(Wh, xp, hbuf, out);
}

// Round 6
// 2690.281 us; speedup vs baseline: 5.5864x; 1.1960x over previous
//
#include <hip/hip_runtime.h>
#include <hip/hip_fp16.h>

#define T_DIM 1024
#define B_DIM 64
#define F_DIM 512
#define H_DIM 512
#define G4    2048
#define HSZ   (B_DIM*H_DIM)   // 32768

typedef _Float16 h16;
typedef unsigned long long u64;
typedef _Float16 v8h __attribute__((ext_vector_type(8)));
typedef _Float16 v4h __attribute__((ext_vector_type(4)));
typedef _Float16 v2h __attribute__((ext_vector_type(2)));
typedef float    v4f __attribute__((ext_vector_type(4)));

// workspace layout (bytes):
//   [0, 256MB)            xp arranged: h16 [T][256 wg][2 tile][64 lane][4 reg]
//   [+0, +256KB)          hbuf: u64 [2 phase][4 group][4096 word] tagged h
//   [+256KB, +64MB)       X16: fp16 copy of X [B][T][F]
//   [+, +2MB)             Wxp: fp16 permuted Wx [2048 pc][512 k]
#define XP_HALVES ((size_t)T_DIM * 256 * 2 * 64 * 4)
#define XP_BYTES  (XP_HALVES * 2)
#define HB_WORDS  ((size_t)2 * 4 * 4096)
#define HB_BYTES  (HB_WORDS * 8)       // 256 KB
#define X16_BYTES ((size_t)B_DIM * T_DIM * F_DIM * 2)   // 64 MB
#define WXP_BYTES ((size_t)G4 * F_DIM * 2)              // 2 MB

// ---------------------------------------------------------------------------
// Phase 0a: X fp32 -> fp16, straight copy (bandwidth-bound).
// ---------------------------------------------------------------------------
__global__ __launch_bounds__(256) void conv_x_kernel(
    const float* __restrict__ X, h16* __restrict__ X16)
{
  const size_t total4 = (size_t)B_DIM * T_DIM * F_DIM / 4;   // 8388608
  for (size_t i = blockIdx.x * 256 + threadIdx.x; i < total4;
       i += (size_t)gridDim.x * 256) {
    float4 v = ((const float4*)X)[i];
    v4h w = { (h16)v.x, (h16)v.y, (h16)v.z, (h16)v.w };
    ((v4h*)X16)[i] = w;
  }
}

// ---------------------------------------------------------------------------
// Phase 0b: Wx fp32 -> Wxp[pc][k] fp16, pre-permuted into staging order.
// pc -> gcol: ub=pc>>5, Tt=(pc>>4)&1, nn=pc&15,
//             gcol=(Tt*2+(nn>>3))*512 + ub*8 + (nn&7).
// Writes: lane = k-oct -> 1KB contiguous per pc. Reads: scalar column walk,
// LLC-absorbed (Wx is 4MB).
// ---------------------------------------------------------------------------
__global__ __launch_bounds__(256) void conv_w_kernel(
    const float* __restrict__ Wx, h16* __restrict__ Wxp)
{
  const int gid = blockIdx.x * 256 + threadIdx.x;   // 512 blocks -> 131072
  const int pcg = gid >> 6;                         // 0..2047
  const int k8  = gid & 63;                         // 0..63 (8 k's each)
  const int ub  = pcg >> 5, Tt = (pcg >> 4) & 1, nn = pcg & 15;
  const int gcol = (Tt*2 + (nn >> 3))*512 + ub*8 + (nn & 7);
  v8h w;
  #pragma unroll
  for (int j = 0; j < 8; ++j)
    w[j] = (h16)Wx[(size_t)(k8*8 + j)*G4 + gcol];
  *(v8h*)(Wxp + (size_t)pcg*512 + k8*8) = w;
}

// ---------------------------------------------------------------------------
// Phase 1: x_proj = X16 @ Wxp + b -> fp16 MFMA C/D fragment layout.
// Staging is now pure 16B copies (no converts, no scalar gathers);
// MFMA indexing / LDS geometry / epilogue identical to round 5.
// ---------------------------------------------------------------------------
__global__ __launch_bounds__(256) void xproj_kernel(
    const h16* __restrict__ X16, const h16* __restrict__ Wxp,
    const float* __restrict__ bias, h16* __restrict__ xp)
{
  __shared__ __align__(16) h16 As[128*72];   // [m 0..127][k 0..63], pad 72
  __shared__ __align__(16) h16 Bs[128*72];   // [pc 0..127][k 0..63], pad 72
  const int wgid = blockIdx.x;               // 8192 blocks
  const int wgn  = wgid & 15;                // Wx-column block (128 pc)
  const int bg   = (wgid >> 4) & 3;          // batch group (16 rows)
  const int t0   = (wgid >> 6) * 8;          // 8 consecutive t per WG
  const int tid  = threadIdx.x;
  const int lane = tid & 63;
  const int wv   = tid >> 6;
  const int mh   = wv & 1, nh = wv >> 1;
  const int n    = lane & 15, quad = lane >> 4;

  v4f acc[4][4];
  #pragma unroll
  for (int mi = 0; mi < 4; ++mi)
    #pragma unroll
    for (int ni = 0; ni < 4; ++ni) acc[mi][ni] = {0.f, 0.f, 0.f, 0.f};

  const int m  = tid >> 1;        // row 0..127 (A: m, B: pc)
  const int kh = tid & 1;         // k half (32 fp16 = 64 B)
  const int abl = m & 15, atl = m >> 4;
  const h16* asrc0 = X16 + ((size_t)(bg*16 + abl)*T_DIM + (t0 + atl))*F_DIM
                         + kh*32;
  const h16* bsrc0 = Wxp + (size_t)(wgn*128 + m)*512 + kh*32;
  h16* adst = As + m*72 + kh*32;
  h16* bdst = Bs + m*72 + kh*32;

  for (int kc = 0; kc < 8; ++kc) {
    __syncthreads();
    {
      const h16* asrc = asrc0 + kc*64;
      const h16* bsrc = bsrc0 + kc*64;
      #pragma unroll
      for (int j = 0; j < 32; j += 8) {
        *(v8h*)(adst + j) = *(const v8h*)(asrc + j);
        *(v8h*)(bdst + j) = *(const v8h*)(bsrc + j);
      }
    }
    __syncthreads();
    #pragma unroll
    for (int kk = 0; kk < 2; ++kk) {
      v8h aF[4], bF[4];
      #pragma unroll
      for (int mi = 0; mi < 4; ++mi)
        aF[mi] = *(const v8h*)(As + ((mh*4 + mi)*16 + n)*72 + kk*32 + quad*8);
      #pragma unroll
      for (int ni = 0; ni < 4; ++ni)
        bF[ni] = *(const v8h*)(Bs + ((nh*4 + ni)*16 + n)*72 + kk*32 + quad*8);
      #pragma unroll
      for (int mi = 0; mi < 4; ++mi)
        #pragma unroll
        for (int ni = 0; ni < 4; ++ni)
          acc[mi][ni] = __builtin_amdgcn_mfma_f32_16x16x32_f16(
              aF[mi], bF[ni], acc[mi][ni], 0, 0, 0);
    }
  }
  #pragma unroll
  for (int ni = 0; ni < 4; ++ni) {
    int pc0  = wgn*128 + (nh*4 + ni)*16;
    int ub   = pc0 >> 5, Tt = (pc0 >> 4) & 1;
    int gcol = (Tt*2 + (n >> 3))*512 + ub*8 + (n & 7);
    float bv = bias[gcol];
    int wg2  = bg*64 + ub;
    #pragma unroll
    for (int mi = 0; mi < 4; ++mi) {
      int t = t0 + mh*4 + mi;
      size_t off = ((((size_t)t*256 + wg2)*2 + Tt)*256) + lane*4;
      v4h o = { (h16)(acc[mi][ni][0] + bv), (h16)(acc[mi][ni][1] + bv),
                (h16)(acc[mi][ni][2] + bv), (h16)(acc[mi][ni][3] + bv) };
      *(v4h*)(xp + off) = o;
    }
  }
}

// ---------------------------------------------------------------------------
// Phase 2: persistent scan (unchanged from round 5).
// 64 WGs x 256 threads; group g = bx>>4 (16 rows), unit-block w = bx&15.
// Tagged u64 words, frag-ordered; cooperative fetch + LDS redistribute.
// ---------------------------------------------------------------------------
__device__ __forceinline__ float fsig(float x) {
  return __builtin_amdgcn_rcpf(1.f + __expf(-x));
}
__device__ __forceinline__ float ftanh(float x) {
  return 1.f - 2.f * __builtin_amdgcn_rcpf(__expf(2.f*x) + 1.f);
}

__global__ __launch_bounds__(256, 1) void scan_kernel(
    const float* __restrict__ Wh, const h16* __restrict__ xp,
    u64* __restrict__ hbuf, float* __restrict__ out)
{
  const int bx   = blockIdx.x;          // 0..63
  const int g    = bx >> 4, w = bx & 15;
  const int tid  = threadIdx.x;         // 0..255
  const int wv   = tid >> 6;
  const int lane = tid & 63;
  const int n    = lane & 15, quad = lane >> 4;
  const int ub   = w*4 + wv;            // 8-unit block 0..63
  const int r0   = g*16,  u0 = ub*8;

  __shared__ unsigned hlds[2][4096];    // payload dwords, frag-ordered, dbuf
  __shared__ float gbuf[4][16*33];      // per-wave gate exchange

  // persistent B fragments: tile0 = gates {i,f}, tile1 = {g,o}
  v8h bF0[16], bF1[16];
  {
    const int g01 = n >> 3;
    const int uc  = u0 + (n & 7);
    #pragma unroll
    for (int kk = 0; kk < 16; ++kk) {
      const int kb = kk*32 + quad*8;
      v8h f0, f1;
      #pragma unroll
      for (int j = 0; j < 8; ++j) {
        f0[j] = (h16)Wh[(size_t)(kb + j)*G4 + (g01*512 + uc)];
        f1[j] = (h16)Wh[(size_t)(kb + j)*G4 + ((2 + g01)*512 + uc)];
      }
      bF0[kk] = f0; bF1[kk] = f1;
    }
  }

  float c0 = 0.f, c1 = 0.f, hf0 = 0.f, hf1 = 0.f;

  // producer slot: unit-pair p = w*16 + wv*4 + quad, row n ->
  // W = w*256 + wv*64 + n*4 + quad  (coalesced per wave instr)
  const int pslot = w*256 + wv*64 + n*4 + quad;

  // preload first xp fragment
  size_t xoff = ((size_t)(g*64 + ub)*2)*256 + lane*4;
  v4h x0 = *(const v4h*)(xp + xoff);
  v4h x1 = *(const v4h*)(xp + xoff + 256);

  for (int t = 0; t < T_DIM; ++t) {
    const int p = t & 1;

    // prefetch next step's xp first: HBM latency hides under the poll
    v4h nx0 = x0, nx1 = x1;
    if (t + 1 < T_DIM) {
      size_t nxo = (((size_t)(t+1)*256 + g*64 + ub)*2)*256 + lane*4;
      nx0 = *(const v4h*)(xp + nxo);
      nx1 = *(const v4h*)(xp + nxo + 256);
    }

    // cooperative poll: this thread owns words j*256+tid (j=0..15);
    // each wave-instr reads 512 B contiguous
    const u64* hb = hbuf + ((size_t)p*4 + g)*4096 + tid;
    u64 wq[16];
    {
      const unsigned target = (unsigned)t;
      for (;;) {
        #pragma unroll
        for (int j = 0; j < 16; ++j)
          wq[j] = __hip_atomic_load(hb + j*256, __ATOMIC_RELAXED,
                                    __HIP_MEMORY_SCOPE_AGENT);
        unsigned bad = 0;
        #pragma unroll
        for (int j = 0; j < 16; ++j)
          bad |= ((unsigned)(wq[j] >> 32)) ^ target;
        if (__all((int)(bad == 0))) break;
        __builtin_amdgcn_s_sleep(1);
      }
    }
    // redistribute payloads (conflict-free: bank = tid%32)
    {
      unsigned* hl = &hlds[p][tid];
      #pragma unroll
      for (int j = 0; j < 16; ++j) hl[j*256] = (unsigned)wq[j];
    }
    __syncthreads();

    v4f acc0 = { (float)x0[0], (float)x0[1], (float)x0[2], (float)x0[3] };
    v4f acc1 = { (float)x1[0], (float)x1[1], (float)x1[2], (float)x1[3] };
    v4f acc2 = { 0.f, 0.f, 0.f, 0.f };
    v4f acc3 = { 0.f, 0.f, 0.f, 0.f };
    const unsigned* hfr = &hlds[p][quad*64 + n*4];
    #pragma unroll
    for (int kk = 0; kk < 8; ++kk) {
      v8h a0 = *(const v8h*)(hfr + kk*256);
      v8h a1 = *(const v8h*)(hfr + (kk+8)*256);
      acc0 = __builtin_amdgcn_mfma_f32_16x16x32_f16(a0, bF0[kk],   acc0, 0,0,0);
      acc1 = __builtin_amdgcn_mfma_f32_16x16x32_f16(a0, bF1[kk],   acc1, 0,0,0);
      acc2 = __builtin_amdgcn_mfma_f32_16x16x32_f16(a1, bF0[kk+8], acc2, 0,0,0);
      acc3 = __builtin_amdgcn_mfma_f32_16x16x32_f16(a1, bF1[kk+8], acc3, 0,0,0);
    }
    acc0 += acc2; acc1 += acc3;

    // gate exchange within wave: C/D layout col=lane&15, row=quad*4+reg
    float* gb = gbuf[wv];
    #pragma unroll
    for (int r = 0; r < 4; ++r) {
      const int row = quad*4 + r;
      gb[row*33 + n]      = acc0[r];   // gates 0,1 (cols 0..15)
      gb[row*33 + 16 + n] = acc1[r];   // gates 2,3 (cols 16..31)
    }
    __builtin_amdgcn_wave_barrier();   // per-wave region: in-order LDS
    const float* gr = gb + n*33;       // this lane's row r = n
    const int ua2 = quad*2;            // local units ua2, ua2+1
    float gi0 = gr[ua2],   gf0 = gr[8+ua2], gg0 = gr[16+ua2], go0 = gr[24+ua2];
    float gi1 = gr[ua2+1], gf1 = gr[9+ua2], gg1 = gr[17+ua2], go1 = gr[25+ua2];
    __builtin_amdgcn_wave_barrier();

    gi0 = fsig(gi0); gf0 = fsig(gf0); gg0 = ftanh(gg0); go0 = fsig(go0);
    gi1 = fsig(gi1); gf1 = fsig(gf1); gg1 = ftanh(gg1); go1 = fsig(go1);
    c0 = gf0*c0 + gi0*gg0;  hf0 = go0*ftanh(c0);
    c1 = gf1*c1 + gi1*gg1;  hf1 = go1*ftanh(c1);

    // tagged h store: {hi: t+1, lo: 2 fp16} — single 8B relaxed agent store
    if (t < T_DIM - 1) {
      union { v2h v; unsigned u; } pw;
      pw.v = (v2h){ (h16)hf0, (h16)hf1 };
      u64 word = ((u64)(unsigned)(t + 1) << 32) | (u64)pw.u;
      u64* hwp = hbuf + ((size_t)(p^1)*4 + g)*4096 + pslot;
      __hip_atomic_store(hwp, word, __ATOMIC_RELAXED, __HIP_MEMORY_SCOPE_AGENT);
    }
    x0 = nx0; x1 = nx1;
  }
  // final carry: out[0:32768] = c, out[32768:65536] = h  (fp32)
  float* oc = out + (size_t)(r0 + n)*H_DIM + u0 + quad*2;
  oc[0] = c0; oc[1] = c1;
  oc[HSZ + 0] = hf0; oc[HSZ + 1] = hf1;
}

extern "C" void kernel_launch(void* const* d_in, const int* in_sizes, int n_in,
                              void* d_out, int out_size, void* d_ws, size_t ws_size,
                              hipStream_t stream) {
  const float* X    = (const float*)d_in[0];
  const float* Wx   = (const float*)d_in[1];
  const float* Wh   = (const float*)d_in[2];
  const float* bias = (const float*)d_in[3];
  float* out = (float*)d_out;

  char* ws = (char*)d_ws;
  h16* xp   = (h16*)ws;
  u64* hbuf = (u64*)(ws + XP_BYTES);
  h16* X16  = (h16*)(ws + XP_BYTES + HB_BYTES);
  h16* Wxp  = (h16*)(ws + XP_BYTES + HB_BYTES + X16_BYTES);

  // zero hbuf (tags -> 0 == t=0 target, h -> 0.0); ws is poisoned 0xAA
  hipMemsetAsync(ws + XP_BYTES, 0, HB_BYTES, stream);

  conv_x_kernel<<<4096, 256, 0, stream>>>(X, X16);
  conv_w_kernel<<<512, 256, 0, stream>>>(Wx, Wxp);
  xproj_kernel<<<8192, 256, 0, stream>>>(X16, Wxp, bias, xp);
  scan_kernel<<<64, 256, 0, stream>>>(Wh, xp, hbuf, out);
}